// Round 5
// baseline (536.996 us; speedup 1.0000x reference)
//
#include <hip/hip_runtime.h>
#include <hip/hip_bf16.h>
#include <cstdint>
#include <cstddef>

typedef __bf16 bf16;
typedef __bf16 bf16x8 __attribute__((ext_vector_type(8)));
typedef __bf16 bf16x4 __attribute__((ext_vector_type(4)));
typedef float  f32x4  __attribute__((ext_vector_type(4)));

#define MFMA_BF16(a,b,c) __builtin_amdgcn_mfma_f32_16x16x32_bf16((a),(b),(c),0,0,0)

// dims
#define BB 8
#define TT 16
#define PP 256
#define EE 768
#define HH 12
#define HDD 64
#define NQKV 2304
#define MROWS 32768   // B*T*P

__device__ __forceinline__ void gld_lds16(const bf16* g, bf16* l) {
  __builtin_amdgcn_global_load_lds((const __attribute__((address_space(1))) void*)g,
                                   (__attribute__((address_space(3))) void*)l, 16, 0, 0);
}

// ---------------- x fp32 -> bf16 ----------------
__global__ __launch_bounds__(256) void k_cvt_x(const float* __restrict__ x,
                                               bf16* __restrict__ xb) {
  const int64_t i = (int64_t)blockIdx.x * 256 + threadIdx.x;
  const float4* src = (const float4*)x;
  float4 a = src[i * 2];
  float4 b = src[i * 2 + 1];
  bf16x8 o;
  o[0] = (bf16)a.x; o[1] = (bf16)a.y; o[2] = (bf16)a.z; o[3] = (bf16)a.w;
  o[4] = (bf16)b.x; o[5] = (bf16)b.y; o[6] = (bf16)b.z; o[7] = (bf16)b.w;
  *(bf16x8*)(xb + i * 8) = o;
}

// ---------------- weights -> bf16 transposed (B^T layout rows) ----------------
// wt[n][k]: n in [0,768) Wq, [768,1536) Wk, [1536,2304) Wv, [2304,3072) Wo
__global__ __launch_bounds__(256) void k_wt(const float* __restrict__ Wq,
                                            const float* __restrict__ Wk,
                                            const float* __restrict__ Wv,
                                            const float* __restrict__ Wo,
                                            bf16* __restrict__ wt) {
  __shared__ float tile[32][33];
  const int n0 = blockIdx.x * 32;   // 0..3071
  const int k0 = blockIdx.y * 32;   // 0..767
  const float* W;
  int nc;
  if (n0 < 768)        { W = Wq; nc = n0; }
  else if (n0 < 1536)  { W = Wk; nc = n0 - 768; }
  else if (n0 < 2304)  { W = Wv; nc = n0 - 1536; }
  else                 { W = Wo; nc = n0 - 2304; }
  const int tx = threadIdx.x & 31, ty = threadIdx.x >> 5;
  for (int r = ty; r < 32; r += 8)
    tile[r][tx] = W[(int64_t)(k0 + r) * 768 + nc + tx];
  __syncthreads();
  for (int r = ty; r < 32; r += 8)
    wt[(int64_t)(n0 + r) * 768 + k0 + tx] = (bf16)tile[tx][r];
}

// ---------------- QKV GEMM + bias + RoPE + scatter ----------------
// 256x256 tile, BK=32, 8 waves (2Mx4N), 4-buffer LDS (128 KiB), depth-3 prefetch,
// counted vmcnt(8): tile t's loads retired at top-of-t; t+1/t+2 stay in flight
// ACROSS the barrier (never vmcnt(0) mid-loop). One s_barrier per K-tile.
// LDS chunk-XOR swizzle (64B rows, 4 chunks, key=(row>>1)&3) via pre-swizzled
// global source; 2-way residual bank aliasing = free.
__global__ __launch_bounds__(512, 2) void k_qkv(const bf16* __restrict__ xb,
                                                const bf16* __restrict__ wt,
                                                const float* __restrict__ bq,
                                                const float* __restrict__ bk,
                                                const float* __restrict__ bv,
                                                bf16* __restrict__ qb,
                                                bf16* __restrict__ kb,
                                                bf16* __restrict__ vt) {
  extern __shared__ char smem_raw[];
  bf16* smem = (bf16*)smem_raw;          // 4 bufs x (A:8192 | B:8192) elems = 128 KiB
  const int tid = threadIdx.x;
  const int w = tid >> 6, lane = tid & 63, quad = lane >> 4, l16 = lane & 15;
  const int wr = w >> 2, wc = w & 3;     // 2M x 4N wave grid
  // ---- L2-supertiled decode: 1152 blocks = 8 xcd * 16 m * 9 n (n innermost) ----
  const int bid = blockIdx.x;
  const int xcd = bid & 7;
  const int loc = bid >> 3;              // 0..143
  const int m0  = (xcd * 16 + loc / 9) * 256;
  const int n0  = (loc % 9) * 256;
  // staging: rows of 32 elems (64B); per gld_lds a wave covers 16 rows x 4 chunks.
  // global chunk = (lane&3) ^ key, key = (row>>1)&3 = (lane>>3)&3  (involution)
  const int cg8 = (((lane & 3) ^ ((lane >> 3) & 3)) * 8);
  const bf16* Ag0 = xb + (int64_t)(m0 + w * 16 + (lane >> 2)) * 768 + cg8;
  const bf16* Bg0 = wt + (int64_t)(n0 + w * 16 + (lane >> 2)) * 768 + cg8;

  auto stage = [&](int kt, int b) {
    bf16* LA = smem + b * 16384 + w * 512;
    bf16* LB = LA + 8192;
    const bf16* GA = Ag0 + kt * 32;
    const bf16* GB = Bg0 + kt * 32;
    gld_lds16(GA, LA);
    gld_lds16(GA + 128 * 768, LA + 4096);
    gld_lds16(GB, LB);
    gld_lds16(GB + 128 * 768, LB + 4096);
  };

  f32x4 acc[8][4] = {};
  stage(0, 0);
  stage(1, 1);
  stage(2, 2);
  const int rkey8 = ((l16 >> 1) & 3) * 8;
  for (int t = 0; t < 24; ++t) {
    // retire exactly tile t's 4 loads; keep t+1/t+2 (8 loads) in flight across barrier
    if (t < 22)       { asm volatile("s_waitcnt vmcnt(8)" ::: "memory"); }
    else if (t == 22) { asm volatile("s_waitcnt vmcnt(4)" ::: "memory"); }
    else              { asm volatile("s_waitcnt vmcnt(0)" ::: "memory"); }
    __builtin_amdgcn_s_barrier();
    __builtin_amdgcn_sched_barrier(0);   // cross-wave RAW: no ds_read above barrier
    if (t < 21) stage(t + 3, (t + 3) & 3);  // WAR safe: buf readers done pre-barrier
    const bf16* A = smem + (t & 3) * 16384;
    const bf16* B = A + 8192;
    bf16x8 bfr[4];
#pragma unroll
    for (int ni = 0; ni < 4; ++ni)
      bfr[ni] = *(const bf16x8*)&B[(wc * 64 + ni * 16 + l16) * 32 + ((quad * 8) ^ rkey8)];
    bf16x8 afr[8];
#pragma unroll
    for (int mi = 0; mi < 8; ++mi)
      afr[mi] = *(const bf16x8*)&A[(wr * 128 + mi * 16 + l16) * 32 + ((quad * 8) ^ rkey8)];
    __builtin_amdgcn_s_setprio(1);
#pragma unroll
    for (int mi = 0; mi < 8; ++mi)
#pragma unroll
      for (int ni = 0; ni < 4; ++ni)
        acc[mi][ni] = MFMA_BF16(afr[mi], bfr[ni], acc[mi][ni]);
    __builtin_amdgcn_s_setprio(0);
  }
  // ---- epilogue ----
  const int sec = n0 / 768;            // block-uniform: 0=q 1=k 2=v
  const float* bias_p = (sec == 0) ? bq : (sec == 1) ? bk : bv;
  if (sec == 2) {
#pragma unroll
    for (int ni = 0; ni < 4; ++ni) {
      const int ng = (n0 % 768) + wc * 64 + ni * 16 + l16;  // 0..767
      const int h = ng >> 6, hd = ng & 63;
      const float bias = bias_p[ng];
#pragma unroll
      for (int mi = 0; mi < 8; ++mi) {
        const int rb = m0 + wr * 128 + mi * 16 + quad * 4;
        const int bt = rb >> 8, p = rb & 255;
        bf16x4 pk;
#pragma unroll
        for (int r = 0; r < 4; ++r) pk[r] = (bf16)(acc[mi][ni][r] + bias);
        *(bf16x4*)&vt[((int64_t)(bt * 12 + h) * 64 + hd) * 256 + p] = pk;
      }
    }
  } else {
    bf16* dst = (sec == 0) ? qb : kb;
    const float L2C = 0.83048202372184058696f;  // log2(10000)/16
#pragma unroll
    for (int ni = 0; ni < 4; ++ni) {
      const int ng = (n0 % 768) + wc * 64 + ni * 16 + l16;
      const int h = ng >> 6, hd = ng & 63;
      const float bias = bias_p[ng];
      const int j = (hd & 31) >> 1;
      const float invf = exp2f(-(float)j * L2C);
      const bool odd = (hd & 1);
      const bool isx = (hd < 32);
#pragma unroll
      for (int mi = 0; mi < 8; ++mi) {
        const int rb = m0 + wr * 128 + mi * 16 + quad * 4;
        const int bt = rb >> 8;
        const int pb = rb & 255;
#pragma unroll
        for (int r = 0; r < 4; ++r) {
          const int p = pb + r;
          float v = acc[mi][ni][r] + bias;
          float pv = __shfl_xor(v, 1, 64);  // partner column (n ^ 1), same row
          const int pos = isx ? (p & 15) : (p >> 4);
          float sn, cs;
          __sincosf((float)pos * invf, &sn, &cs);
          float o = odd ? (v * cs + pv * sn) : (v * cs - pv * sn);
          dst[((int64_t)(bt * 12 + h) * 256 + p) * 64 + hd] = (bf16)o;
        }
      }
    }
  }
}

// ---------------- attention: per (b,t,h) block ----------------
// Q,K: (P,HD) row-major per head; V: (HD,P) row-major per head. y overwrites Q.
__global__ __launch_bounds__(256) void k_attn(bf16* qy,
                                              const bf16* __restrict__ kb,
                                              const bf16* __restrict__ vt) {
  __shared__ __align__(16) bf16 plds[4][16 * 264];  // per-wave, stride 264 pads banks
  const int tid = threadIdx.x;
  const int w = tid >> 6, lane = tid & 63, quad = lane >> 4, l16 = lane & 15;
  const int64_t base = (int64_t)blockIdx.x * 16384;  // 256*64
  bf16* Q = qy + base;
  const bf16* K = kb + base;
  const bf16* V = vt + base;
  bf16* pl = plds[w];
  for (int s = 0; s < 4; ++s) {
    const int r0 = w * 64 + s * 16;
    bf16x8 qf0 = *(const bf16x8*)&Q[(r0 + l16) * 64 + quad * 8];
    bf16x8 qf1 = *(const bf16x8*)&Q[(r0 + l16) * 64 + 32 + quad * 8];
    f32x4 sacc[16] = {};
#pragma unroll
    for (int ct = 0; ct < 16; ++ct) {
      bf16x8 kf0 = *(const bf16x8*)&K[(ct * 16 + l16) * 64 + quad * 8];
      bf16x8 kf1 = *(const bf16x8*)&K[(ct * 16 + l16) * 64 + 32 + quad * 8];
      sacc[ct] = MFMA_BF16(qf0, kf0, sacc[ct]);
      sacc[ct] = MFMA_BF16(qf1, kf1, sacc[ct]);
    }
    // softmax over 256 cols; rows live as (quad,reg); cols spread over 16 lanes x 16 tiles
    float mx[4] = {-3e38f, -3e38f, -3e38f, -3e38f};
#pragma unroll
    for (int ct = 0; ct < 16; ++ct)
#pragma unroll
      for (int r = 0; r < 4; ++r) mx[r] = fmaxf(mx[r], sacc[ct][r]);
#pragma unroll
    for (int d = 1; d < 16; d <<= 1)
#pragma unroll
      for (int r = 0; r < 4; ++r) mx[r] = fmaxf(mx[r], __shfl_xor(mx[r], d, 64));
    float sm[4] = {0.f, 0.f, 0.f, 0.f};
#pragma unroll
    for (int ct = 0; ct < 16; ++ct)
#pragma unroll
      for (int r = 0; r < 4; ++r) {
        float e = __expf((sacc[ct][r] - mx[r]) * 0.125f);
        sacc[ct][r] = e;
        sm[r] += e;
      }
#pragma unroll
    for (int d = 1; d < 16; d <<= 1)
#pragma unroll
      for (int r = 0; r < 4; ++r) sm[r] += __shfl_xor(sm[r], d, 64);
    // P: C-layout -> LDS -> A-layout
#pragma unroll
    for (int ct = 0; ct < 16; ++ct)
#pragma unroll
      for (int r = 0; r < 4; ++r)
        pl[(quad * 4 + r) * 264 + ct * 16 + l16] = (bf16)sacc[ct][r];
    __syncthreads();
    f32x4 oacc[4] = {};
#pragma unroll
    for (int kc = 0; kc < 8; ++kc) {
      bf16x8 pf = *(const bf16x8*)&pl[l16 * 264 + kc * 32 + quad * 8];
#pragma unroll
      for (int nt = 0; nt < 4; ++nt) {
        bf16x8 vf = *(const bf16x8*)&V[(nt * 16 + l16) * 256 + kc * 32 + quad * 8];
        oacc[nt] = MFMA_BF16(pf, vf, oacc[nt]);
      }
    }
    float inv[4];
#pragma unroll
    for (int r = 0; r < 4; ++r) inv[r] = 1.0f / sm[r];
#pragma unroll
    for (int nt = 0; nt < 4; ++nt)
#pragma unroll
      for (int r = 0; r < 4; ++r)
        Q[(r0 + quad * 4 + r) * 64 + nt * 16 + l16] = (bf16)(oacc[nt][r] * inv[r]);
    __syncthreads();
  }
}

// ---------------- out GEMM: y(b,t,h,p,hd) @ Wo -> d_out fp32 ----------------
// Port of the round-3-VERIFIED 2-phase 256-tile template: BM=256, BN=128, BK=64,
// 8 waves (4M x 2N), 96 KiB LDS double-buffer, stage-before-compute, chunk-XOR
// swizzle (128B rows, 8 chunks, key=row&7). A K-tile = one head: A is a fully
// contiguous 32 KiB block. 768 blocks = 8 xcd * 16 m * 6 n (n innermost).
__global__ __launch_bounds__(512, 2) void k_out(const bf16* __restrict__ yb,
                                                const bf16* __restrict__ wt,
                                                float* __restrict__ out) {
  extern __shared__ char smem_raw[];
  bf16* smem = (bf16*)smem_raw;          // 2 bufs x (A:16384 | B:8192) elems = 96 KiB
  const int tid = threadIdx.x;
  const int w = tid >> 6, lane = tid & 63, quad = lane >> 4, l16 = lane & 15;
  const int wr = w >> 1, wc = w & 1;     // 4M x 2N wave grid
  const int bid = blockIdx.x;
  const int xcd = bid & 7;
  const int loc = bid >> 3;              // 0..95
  const int m0  = (xcd * 16 + loc / 6) * 256;
  const int n0  = (loc % 6) * 128;
  const int bt  = m0 >> 8;               // one (b,t) per block
  // staging: rows of 64 elems (128B); per gld_lds a wave covers 8 rows x 8 chunks
  const int srow = w * 8 + (lane >> 3);
  const int cgo  = (((lane & 7) ^ ((lane >> 3) & 7)) * 8);
  const bf16* Bg0 = wt + (int64_t)(2304 + n0 + srow) * 768 + cgo;

  auto stage = [&](int kt, int p) {
    bf16* LA = smem + p * 24576 + w * 512;
    bf16* LB = smem + p * 24576 + 16384 + w * 512;
    const bf16* GA = yb + (int64_t)(bt * 12 + kt) * 16384 + srow * 64 + cgo;
    const bf16* GB = Bg0 + kt * 64;
#pragma unroll
    for (int rd = 0; rd < 4; ++rd)
      gld_lds16(GA + rd * 4096, LA + rd * 4096);    // 64 rows per round
#pragma unroll
    for (int rd = 0; rd < 2; ++rd)
      gld_lds16(GB + rd * 49152, LB + rd * 4096);
  };

  f32x4 acc[4][4] = {};
  stage(0, 0);
  __syncthreads();
  const int rkey8 = (l16 & 7) * 8;
  for (int t = 0; t < 12; ++t) {
    if (t < 11) stage(t + 1, (t + 1) & 1);   // overlaps this tile's compute
    __builtin_amdgcn_sched_barrier(0);
    const bf16* A = smem + (t & 1) * 24576;
    const bf16* B = A + 16384;
    bf16x8 bfr[4][2];
#pragma unroll
    for (int ni = 0; ni < 4; ++ni)
#pragma unroll
      for (int kk = 0; kk < 2; ++kk)
        bfr[ni][kk] = *(const bf16x8*)&B[(wc * 64 + ni * 16 + l16) * 64 +
                                         (((kk * 4 + quad) * 8) ^ rkey8)];
    bf16x8 afr[4][2];
#pragma unroll
    for (int mi = 0; mi < 4; ++mi)
#pragma unroll
      for (int kk = 0; kk < 2; ++kk)
        afr[mi][kk] = *(const bf16x8*)&A[(wr * 64 + mi * 16 + l16) * 64 +
                                         (((kk * 4 + quad) * 8) ^ rkey8)];
    __builtin_amdgcn_s_setprio(1);
#pragma unroll
    for (int mi = 0; mi < 4; ++mi)
#pragma unroll
      for (int ni = 0; ni < 4; ++ni)
#pragma unroll
        for (int kk = 0; kk < 2; ++kk)
          acc[mi][ni] = MFMA_BF16(afr[mi][kk], bfr[ni][kk], acc[mi][ni]);
    __builtin_amdgcn_s_setprio(0);
    __syncthreads();
  }
#pragma unroll
  for (int mi = 0; mi < 4; ++mi)
#pragma unroll
    for (int ni = 0; ni < 4; ++ni) {
      const int rg = m0 + wr * 64 + mi * 16 + quad * 4;
      const int cg = n0 + wc * 64 + ni * 16 + l16;
#pragma unroll
      for (int r = 0; r < 4; ++r)
        out[(int64_t)(rg + r) * 768 + cg] = acc[mi][ni][r];
    }
}

extern "C" void kernel_launch(void* const* d_in, const int* in_sizes, int n_in,
                              void* d_out, int out_size, void* d_ws, size_t ws_size,
                              hipStream_t stream) {
  const float* x  = (const float*)d_in[0];
  const float* Wq = (const float*)d_in[1];
  const float* bq = (const float*)d_in[2];
  const float* Wk = (const float*)d_in[3];
  const float* bk = (const float*)d_in[4];
  const float* Wv = (const float*)d_in[5];
  const float* bv = (const float*)d_in[6];
  const float* Wo = (const float*)d_in[7];
  float* out = (float*)d_out;

  uint8_t* ws = (uint8_t*)d_ws;
  const size_t SZ = (size_t)25165824 * 2;        // one (B,T,H,P,HD) bf16 tensor
  bf16* qy = (bf16*)ws;                          // q, later reused as y
  bf16* kb = (bf16*)(ws + SZ);
  bf16* vt = (bf16*)(ws + 2 * SZ);
  bf16* wt = (bf16*)(ws + 3 * SZ);               // 3072x768 bf16
  bf16* xb = (bf16*)d_out;                       // x-bf16 scratch inside output buffer

  static int attr_set = 0;
  if (!attr_set) {
    (void)hipFuncSetAttribute((const void*)k_qkv,
                              hipFuncAttributeMaxDynamicSharedMemorySize, 131072);
    (void)hipFuncSetAttribute((const void*)k_out,
                              hipFuncAttributeMaxDynamicSharedMemorySize, 98304);
    attr_set = 1;
  }

  k_cvt_x<<<12288, 256, 0, stream>>>(x, xb);
  k_wt<<<dim3(96, 24), 256, 0, stream>>>(Wq, Wk, Wv, Wo, wt);
  k_qkv<<<1152, 512, 131072, stream>>>(xb, wt, bq, bk, bv, qy, kb, vt);
  k_attn<<<1536, 256, 0, stream>>>(qy, kb, vt);
  k_out<<<768, 512, 98304, stream>>>(qy, wt, out);
}

// Round 6
// 533.738 us; speedup vs baseline: 1.0061x; 1.0061x over previous
//
#include <hip/hip_runtime.h>
#include <hip/hip_bf16.h>
#include <cstdint>
#include <cstddef>

typedef __bf16 bf16;
typedef __bf16 bf16x8 __attribute__((ext_vector_type(8)));
typedef __bf16 bf16x4 __attribute__((ext_vector_type(4)));
typedef float  f32x4  __attribute__((ext_vector_type(4)));

#define MFMA_BF16(a,b,c) __builtin_amdgcn_mfma_f32_16x16x32_bf16((a),(b),(c),0,0,0)

// dims
#define BB 8
#define TT 16
#define PP 256
#define EE 768
#define HH 12
#define HDD 64
#define NQKV 2304
#define MROWS 32768   // B*T*P

__device__ __forceinline__ void gld_lds16(const bf16* g, bf16* l) {
  __builtin_amdgcn_global_load_lds((const __attribute__((address_space(1))) void*)g,
                                   (__attribute__((address_space(3))) void*)l, 16, 0, 0);
}

// ---------------- x fp32 -> bf16 ----------------
__global__ __launch_bounds__(256) void k_cvt_x(const float* __restrict__ x,
                                               bf16* __restrict__ xb) {
  const int64_t i = (int64_t)blockIdx.x * 256 + threadIdx.x;
  const float4* src = (const float4*)x;
  float4 a = src[i * 2];
  float4 b = src[i * 2 + 1];
  bf16x8 o;
  o[0] = (bf16)a.x; o[1] = (bf16)a.y; o[2] = (bf16)a.z; o[3] = (bf16)a.w;
  o[4] = (bf16)b.x; o[5] = (bf16)b.y; o[6] = (bf16)b.z; o[7] = (bf16)b.w;
  *(bf16x8*)(xb + i * 8) = o;
}

// ---------------- weights -> bf16 transposed (B^T layout rows) ----------------
// wt[n][k]: n in [0,768) Wq, [768,1536) Wk, [1536,2304) Wv, [2304,3072) Wo
__global__ __launch_bounds__(256) void k_wt(const float* __restrict__ Wq,
                                            const float* __restrict__ Wk,
                                            const float* __restrict__ Wv,
                                            const float* __restrict__ Wo,
                                            bf16* __restrict__ wt) {
  __shared__ float tile[32][33];
  const int n0 = blockIdx.x * 32;   // 0..3071
  const int k0 = blockIdx.y * 32;   // 0..767
  const float* W;
  int nc;
  if (n0 < 768)        { W = Wq; nc = n0; }
  else if (n0 < 1536)  { W = Wk; nc = n0 - 768; }
  else if (n0 < 2304)  { W = Wv; nc = n0 - 1536; }
  else                 { W = Wo; nc = n0 - 2304; }
  const int tx = threadIdx.x & 31, ty = threadIdx.x >> 5;
  for (int r = ty; r < 32; r += 8)
    tile[r][tx] = W[(int64_t)(k0 + r) * 768 + nc + tx];
  __syncthreads();
  for (int r = ty; r < 32; r += 8)
    wt[(int64_t)(n0 + r) * 768 + k0 + tx] = (bf16)tile[tx][r];
}

// ---------------- QKV GEMM + bias + RoPE + scatter ----------------
// Main loop: round-4 VERIFIED schedule — 256x256 tile, BK=64, 8 waves (2Mx4N),
// 128 KiB LDS double-buffer, stage(t+1)-before-compute(t), chunk-XOR swizzle.
// NEW epilogue: stage the block's 128 KB output into LDS (16B-chunk XOR swizzle),
// then flush with fully-coalesced bf16x8 stores. Trig hoisted (pos has <=8
// distinct values per thread) — arithmetic bit-identical to the scalar path.
__global__ __launch_bounds__(512, 2) void k_qkv(const bf16* __restrict__ xb,
                                                const bf16* __restrict__ wt,
                                                const float* __restrict__ bq,
                                                const float* __restrict__ bk,
                                                const float* __restrict__ bv,
                                                bf16* __restrict__ qb,
                                                bf16* __restrict__ kb,
                                                bf16* __restrict__ vt) {
  extern __shared__ char smem_raw[];
  bf16* smem = (bf16*)smem_raw;          // [2][A:16384 | B:16384] elements
  const int tid = threadIdx.x;
  const int w = tid >> 6, lane = tid & 63, quad = lane >> 4, l16 = lane & 15;
  const int wr = w >> 2, wc = w & 3;     // 2 x 4 wave grid
  const int kap = l16 & 7;               // per-thread chunk XOR key
  // ---- L2-supertiled decode: 1152 blocks = 8 xcd * 16 m * 9 n (n innermost) ----
  const int bid = blockIdx.x;
  const int xcd = bid & 7;
  const int loc = bid >> 3;              // 0..143
  const int m0  = (xcd * 16 + loc / 9) * 256;
  const int n0  = (loc % 9) * 256;
  // staging: per gld_lds a wave writes 8 LDS rows; lane supplies row lane>>3,
  // chunk lane&7, fetched from global chunk (lane&7)^((lane>>3)&7)  (involution)
  const int srow = w * 8 + (lane >> 3);
  const int cgo  = ((lane & 7) ^ ((lane >> 3) & 7)) * 8;
  const bf16* Ag = xb + (int64_t)(m0 + srow) * 768 + cgo;
  const bf16* Bg = wt + (int64_t)(n0 + srow) * 768 + cgo;

  auto stage = [&](int kt, int p) {
    bf16* LA = smem + p * 32768 + w * 512;
    bf16* LB = LA + 16384;
    const bf16* GA = Ag + kt * 64;
    const bf16* GB = Bg + kt * 64;
#pragma unroll
    for (int rd = 0; rd < 4; ++rd) {
      gld_lds16(GA + rd * 49152, LA + rd * 4096);   // 64 rows per round
      gld_lds16(GB + rd * 49152, LB + rd * 4096);
    }
  };

  f32x4 acc[8][4] = {};
  stage(0, 0);
  __syncthreads();
  for (int t = 0; t < 12; ++t) {
    if (t < 11) stage(t + 1, (t + 1) & 1);      // overlaps this tile's compute
    __builtin_amdgcn_sched_barrier(0);          // keep stage issue early
    const bf16* A = smem + (t & 1) * 32768;
    const bf16* B = A + 16384;
    bf16x8 bfr[4][2];
#pragma unroll
    for (int ni = 0; ni < 4; ++ni)
#pragma unroll
      for (int kk = 0; kk < 2; ++kk)
        bfr[ni][kk] = *(const bf16x8*)&B[(wc * 64 + ni * 16 + l16) * 64 +
                                         (((kk * 4 + quad) ^ kap) * 8)];
#pragma unroll
    for (int mh = 0; mh < 2; ++mh) {
      bf16x8 afr[4][2];
#pragma unroll
      for (int mi = 0; mi < 4; ++mi)
#pragma unroll
        for (int kk = 0; kk < 2; ++kk)
          afr[mi][kk] = *(const bf16x8*)&A[(wr * 128 + mh * 64 + mi * 16 + l16) * 64 +
                                           (((kk * 4 + quad) ^ kap) * 8)];
      __builtin_amdgcn_s_setprio(1);
#pragma unroll
      for (int mi = 0; mi < 4; ++mi)
#pragma unroll
        for (int ni = 0; ni < 4; ++ni)
#pragma unroll
          for (int kk = 0; kk < 2; ++kk)
            acc[mh * 4 + mi][ni] = MFMA_BF16(afr[mi][kk], bfr[ni][kk], acc[mh * 4 + mi][ni]);
      __builtin_amdgcn_s_setprio(0);
    }
    __syncthreads();   // drains vmcnt: stage(t+1) had the whole compute to land
  }
  // ---- epilogue: LDS-staged coalesced writes ----
  // After the final __syncthreads all LDS reads/writes of the K-loop are done:
  // reuse the 128 KiB as output staging (4 heads x 32 KB, contiguous per head).
  const int sec = n0 / 768;            // block-uniform: 0=q 1=k 2=v
  const int h0 = (n0 % 768) >> 6;      // first head of this block's n-range
  const float* bias_p = (sec == 0) ? bq : (sec == 1) ? bk : bv;
  char* eb = (char*)smem;
  const int64_t obase = (int64_t)(m0 >> 8) * 12 * 16384;  // bt * 12 heads * 64*256
  if (sec == 2) {
    // stage v as [hh][hd][p] (rows 512B), 16B-chunk swizzle: chunk' = (p>>3)^(hd&15)
#pragma unroll
    for (int ni = 0; ni < 4; ++ni) {
      const int nn = wc * 64 + ni * 16 + l16;   // 0..255
      const int hh = nn >> 6, hd = nn & 63;
      const float bias = bias_p[(n0 % 768) + nn];
#pragma unroll
      for (int mi = 0; mi < 8; ++mi) {
        const int p = wr * 128 + mi * 16 + quad * 4;   // local row 0..255 (r in-vec)
        bf16x4 pk;
#pragma unroll
        for (int r = 0; r < 4; ++r) pk[r] = (bf16)(acc[mi][ni][r] + bias);
        *(bf16x4*)(eb + hh * 32768 + hd * 512 +
                   ((((p >> 3) ^ (hd & 15)) << 4) | (((p >> 2) & 1) << 3))) = pk;
      }
    }
    __syncthreads();
#pragma unroll
    for (int it = 0; it < 16; ++it) {
      const int lin = (it * 512 + tid) * 16;   // byte offset in LDS
      const int hh = lin >> 15;
      const int rem = lin & 32767;
      const int hd = rem >> 9;
      const int cs = (rem >> 4) & 31;
      const int pc = cs ^ (hd & 15);           // un-swizzle: global p-chunk
      bf16x8 val = *(const bf16x8*)(eb + lin);
      *(bf16x8*)&vt[obase + ((int64_t)(h0 + hh) * 64 + hd) * 256 + pc * 8] = val;
    }
  } else {
    bf16* dst = (sec == 0) ? qb : kb;
    const float L2C = 0.83048202372184058696f;  // log2(10000)/16
    // stage q/k as [hh][p][hd] (rows 128B), 16B-chunk swizzle: chunk' = (hd>>3)^(p&7)
#pragma unroll
    for (int ni = 0; ni < 4; ++ni) {
      const int nn = wc * 64 + ni * 16 + l16;
      const int hh = nn >> 6, hd = nn & 63;
      const float bias = bias_p[(n0 % 768) + nn];
      const int j = (hd & 31) >> 1;
      const float invf = exp2f(-(float)j * L2C);
      const bool odd = (hd & 1);
      const bool isx = (hd < 32);
      // pos = isx ? (p&15) = quad*4+r  :  (p>>4) = wr*8+mi  — hoist sincos
      float snt[8], cst[8];
      if (isx) {
#pragma unroll
        for (int r = 0; r < 4; ++r)
          __sincosf((float)(quad * 4 + r) * invf, &snt[r], &cst[r]);
      } else {
#pragma unroll
        for (int mi = 0; mi < 8; ++mi)
          __sincosf((float)(wr * 8 + mi) * invf, &snt[mi], &cst[mi]);
      }
#pragma unroll
      for (int mi = 0; mi < 8; ++mi) {
#pragma unroll
        for (int r = 0; r < 4; ++r) {
          const int p = wr * 128 + mi * 16 + quad * 4 + r;  // local row 0..255
          float v = acc[mi][ni][r] + bias;
          float pv = __shfl_xor(v, 1, 64);  // partner column (hd ^ 1), same row
          const float sn = isx ? snt[r] : snt[mi];
          const float cz = isx ? cst[r] : cst[mi];
          float o = odd ? (v * cz + pv * sn) : (v * cz - pv * sn);
          *(bf16*)(eb + hh * 32768 + p * 128 +
                   ((((hd >> 3) ^ (p & 7)) << 4) | ((hd & 7) << 1))) = (bf16)o;
        }
      }
    }
    __syncthreads();
#pragma unroll
    for (int it = 0; it < 16; ++it) {
      const int lin = (it * 512 + tid) * 16;
      const int hh = lin >> 15;
      const int rem = lin & 32767;
      const int p = rem >> 7;
      const int cs = (rem >> 4) & 7;
      const int hc = cs ^ (p & 7);             // un-swizzle: global hd-chunk
      bf16x8 val = *(const bf16x8*)(eb + lin);
      *(bf16x8*)&dst[obase + ((int64_t)(h0 + hh) * 256 + p) * 64 + hc * 8] = val;
    }
  }
}

// ---------------- attention: per (b,t,h) block ----------------
// Q,K: (P,HD) row-major per head; V: (HD,P) row-major per head. y overwrites Q.
// Waves fully independent (per-wave LDS slice, per-wave Q rows): no block
// barriers, only in-wave lgkmcnt fences for the LDS P round-trip (correctness
// verified on HW in round 2). T5 setprio around MFMA clusters.
__global__ __launch_bounds__(256) void k_attn(bf16* qy,
                                              const bf16* __restrict__ kb,
                                              const bf16* __restrict__ vt) {
  __shared__ __align__(16) bf16 plds[4][16 * 264];  // per-wave, stride 264 pads banks
  const int tid = threadIdx.x;
  const int w = tid >> 6, lane = tid & 63, quad = lane >> 4, l16 = lane & 15;
  const int64_t base = (int64_t)blockIdx.x * 16384;  // 256*64
  bf16* Q = qy + base;
  const bf16* K = kb + base;
  const bf16* V = vt + base;
  bf16* pl = plds[w];
  for (int s = 0; s < 4; ++s) {
    const int r0 = w * 64 + s * 16;
    bf16x8 qf0 = *(const bf16x8*)&Q[(r0 + l16) * 64 + quad * 8];
    bf16x8 qf1 = *(const bf16x8*)&Q[(r0 + l16) * 64 + 32 + quad * 8];
    f32x4 sacc[16] = {};
    __builtin_amdgcn_s_setprio(1);
#pragma unroll
    for (int ct = 0; ct < 16; ++ct) {
      bf16x8 kf0 = *(const bf16x8*)&K[(ct * 16 + l16) * 64 + quad * 8];
      bf16x8 kf1 = *(const bf16x8*)&K[(ct * 16 + l16) * 64 + 32 + quad * 8];
      sacc[ct] = MFMA_BF16(qf0, kf0, sacc[ct]);
      sacc[ct] = MFMA_BF16(qf1, kf1, sacc[ct]);
    }
    __builtin_amdgcn_s_setprio(0);
    // softmax over 256 cols; rows live as (quad,reg); cols spread over 16 lanes x 16 tiles
    float mx[4] = {-3e38f, -3e38f, -3e38f, -3e38f};
#pragma unroll
    for (int ct = 0; ct < 16; ++ct)
#pragma unroll
      for (int r = 0; r < 4; ++r) mx[r] = fmaxf(mx[r], sacc[ct][r]);
#pragma unroll
    for (int d = 1; d < 16; d <<= 1)
#pragma unroll
      for (int r = 0; r < 4; ++r) mx[r] = fmaxf(mx[r], __shfl_xor(mx[r], d, 64));
    float sm[4] = {0.f, 0.f, 0.f, 0.f};
#pragma unroll
    for (int ct = 0; ct < 16; ++ct)
#pragma unroll
      for (int r = 0; r < 4; ++r) {
        float e = __expf((sacc[ct][r] - mx[r]) * 0.125f);
        sacc[ct][r] = e;
        sm[r] += e;
      }
#pragma unroll
    for (int d = 1; d < 16; d <<= 1)
#pragma unroll
      for (int r = 0; r < 4; ++r) sm[r] += __shfl_xor(sm[r], d, 64);
    // P: C-layout -> LDS -> A-layout (same-wave cross-lane round-trip)
#pragma unroll
    for (int ct = 0; ct < 16; ++ct)
#pragma unroll
      for (int r = 0; r < 4; ++r)
        pl[(quad * 4 + r) * 264 + ct * 16 + l16] = (bf16)sacc[ct][r];
    asm volatile("s_waitcnt lgkmcnt(0)" ::: "memory");  // in-wave: writes landed
    __builtin_amdgcn_sched_barrier(0);
    f32x4 oacc[4] = {};
    __builtin_amdgcn_s_setprio(1);
#pragma unroll
    for (int kc = 0; kc < 8; ++kc) {
      bf16x8 pf = *(const bf16x8*)&pl[l16 * 264 + kc * 32 + quad * 8];
#pragma unroll
      for (int nt = 0; nt < 4; ++nt) {
        bf16x8 vf = *(const bf16x8*)&V[(nt * 16 + l16) * 256 + kc * 32 + quad * 8];
        oacc[nt] = MFMA_BF16(pf, vf, oacc[nt]);
      }
    }
    __builtin_amdgcn_s_setprio(0);
    float inv[4];
#pragma unroll
    for (int r = 0; r < 4; ++r) inv[r] = 1.0f / sm[r];
#pragma unroll
    for (int nt = 0; nt < 4; ++nt)
#pragma unroll
      for (int r = 0; r < 4; ++r)
        Q[(r0 + quad * 4 + r) * 64 + nt * 16 + l16] = (bf16)(oacc[nt][r] * inv[r]);
    asm volatile("" ::: "memory");  // keep next-s pl writes below this-s pl reads
  }
}

// ---------------- out GEMM: y(b,t,h,p,hd) @ Wo -> d_out fp32 ----------------
// 2-phase 256-tile template: BM=256, BN=128, BK=64, 8 waves (4M x 2N), 96 KiB
// LDS double-buffer, stage-before-compute, chunk-XOR swizzle. A K-tile = one
// head: A is a fully contiguous 32 KiB block. 768 blocks = 8 xcd * 16 m * 6 n.
__global__ __launch_bounds__(512, 2) void k_out(const bf16* __restrict__ yb,
                                                const bf16* __restrict__ wt,
                                                float* __restrict__ out) {
  extern __shared__ char smem_raw[];
  bf16* smem = (bf16*)smem_raw;          // 2 bufs x (A:16384 | B:8192) elems = 96 KiB
  const int tid = threadIdx.x;
  const int w = tid >> 6, lane = tid & 63, quad = lane >> 4, l16 = lane & 15;
  const int wr = w >> 1, wc = w & 1;     // 4M x 2N wave grid
  const int bid = blockIdx.x;
  const int xcd = bid & 7;
  const int loc = bid >> 3;              // 0..95
  const int m0  = (xcd * 16 + loc / 6) * 256;
  const int n0  = (loc % 6) * 128;
  const int bt  = m0 >> 8;               // one (b,t) per block
  // staging: rows of 64 elems (128B); per gld_lds a wave covers 8 rows x 8 chunks
  const int srow = w * 8 + (lane >> 3);
  const int cgo  = (((lane & 7) ^ ((lane >> 3) & 7)) * 8);
  const bf16* Bg0 = wt + (int64_t)(2304 + n0 + srow) * 768 + cgo;

  auto stage = [&](int kt, int p) {
    bf16* LA = smem + p * 24576 + w * 512;
    bf16* LB = smem + p * 24576 + 16384 + w * 512;
    const bf16* GA = yb + (int64_t)(bt * 12 + kt) * 16384 + srow * 64 + cgo;
    const bf16* GB = Bg0 + kt * 64;
#pragma unroll
    for (int rd = 0; rd < 4; ++rd)
      gld_lds16(GA + rd * 4096, LA + rd * 4096);    // 64 rows per round
#pragma unroll
    for (int rd = 0; rd < 2; ++rd)
      gld_lds16(GB + rd * 49152, LB + rd * 4096);
  };

  f32x4 acc[4][4] = {};
  stage(0, 0);
  __syncthreads();
  const int rkey8 = (l16 & 7) * 8;
  for (int t = 0; t < 12; ++t) {
    if (t < 11) stage(t + 1, (t + 1) & 1);   // overlaps this tile's compute
    __builtin_amdgcn_sched_barrier(0);
    const bf16* A = smem + (t & 1) * 24576;
    const bf16* B = A + 16384;
    bf16x8 bfr[4][2];
#pragma unroll
    for (int ni = 0; ni < 4; ++ni)
#pragma unroll
      for (int kk = 0; kk < 2; ++kk)
        bfr[ni][kk] = *(const bf16x8*)&B[(wc * 64 + ni * 16 + l16) * 64 +
                                         (((kk * 4 + quad) * 8) ^ rkey8)];
    bf16x8 afr[4][2];
#pragma unroll
    for (int mi = 0; mi < 4; ++mi)
#pragma unroll
      for (int kk = 0; kk < 2; ++kk)
        afr[mi][kk] = *(const bf16x8*)&A[(wr * 64 + mi * 16 + l16) * 64 +
                                         (((kk * 4 + quad) * 8) ^ rkey8)];
    __builtin_amdgcn_s_setprio(1);
#pragma unroll
    for (int mi = 0; mi < 4; ++mi)
#pragma unroll
      for (int ni = 0; ni < 4; ++ni)
#pragma unroll
        for (int kk = 0; kk < 2; ++kk)
          acc[mi][ni] = MFMA_BF16(afr[mi][kk], bfr[ni][kk], acc[mi][ni]);
    __builtin_amdgcn_s_setprio(0);
    __syncthreads();
  }
#pragma unroll
  for (int mi = 0; mi < 4; ++mi)
#pragma unroll
    for (int ni = 0; ni < 4; ++ni) {
      const int rg = m0 + wr * 64 + mi * 16 + quad * 4;
      const int cg = n0 + wc * 64 + ni * 16 + l16;
#pragma unroll
      for (int r = 0; r < 4; ++r)
        out[(int64_t)(rg + r) * 768 + cg] = acc[mi][ni][r];
    }
}

extern "C" void kernel_launch(void* const* d_in, const int* in_sizes, int n_in,
                              void* d_out, int out_size, void* d_ws, size_t ws_size,
                              hipStream_t stream) {
  const float* x  = (const float*)d_in[0];
  const float* Wq = (const float*)d_in[1];
  const float* bq = (const float*)d_in[2];
  const float* Wk = (const float*)d_in[3];
  const float* bk = (const float*)d_in[4];
  const float* Wv = (const float*)d_in[5];
  const float* bv = (const float*)d_in[6];
  const float* Wo = (const float*)d_in[7];
  float* out = (float*)d_out;

  uint8_t* ws = (uint8_t*)d_ws;
  const size_t SZ = (size_t)25165824 * 2;        // one (B,T,H,P,HD) bf16 tensor
  bf16* qy = (bf16*)ws;                          // q, later reused as y
  bf16* kb = (bf16*)(ws + SZ);
  bf16* vt = (bf16*)(ws + 2 * SZ);
  bf16* wt = (bf16*)(ws + 3 * SZ);               // 3072x768 bf16
  bf16* xb = (bf16*)d_out;                       // x-bf16 scratch inside output buffer

  static int attr_set = 0;
  if (!attr_set) {
    (void)hipFuncSetAttribute((const void*)k_qkv,
                              hipFuncAttributeMaxDynamicSharedMemorySize, 131072);
    (void)hipFuncSetAttribute((const void*)k_out,
                              hipFuncAttributeMaxDynamicSharedMemorySize, 98304);
    attr_set = 1;
  }

  k_cvt_x<<<12288, 256, 0, stream>>>(x, xb);
  k_wt<<<dim3(96, 24), 256, 0, stream>>>(Wq, Wk, Wv, Wo, wt);
  k_qkv<<<1152, 512, 131072, stream>>>(xb, wt, bq, bk, bv, qy, kb, vt);
  k_attn<<<1536, 256, 0, stream>>>(qy, kb, vt);
  k_out<<<768, 512, 98304, stream>>>(qy, wt, out);
}

// Round 7
// 452.532 us; speedup vs baseline: 1.1866x; 1.1794x over previous
//
#include <hip/hip_runtime.h>
#include <hip/hip_bf16.h>
#include <cstdint>
#include <cstddef>

typedef __bf16 bf16;
typedef __bf16 bf16x8 __attribute__((ext_vector_type(8)));
typedef __bf16 bf16x4 __attribute__((ext_vector_type(4)));
typedef float  f32x4  __attribute__((ext_vector_type(4)));

#define MFMA_BF16(a,b,c) __builtin_amdgcn_mfma_f32_16x16x32_bf16((a),(b),(c),0,0,0)

// dims
#define BB 8
#define TT 16
#define PP 256
#define EE 768
#define HH 12
#define HDD 64
#define NQKV 2304
#define MROWS 32768   // B*T*P

__device__ __forceinline__ void gld_lds16(const bf16* g, bf16* l) {
  __builtin_amdgcn_global_load_lds((const __attribute__((address_space(1))) void*)g,
                                   (__attribute__((address_space(3))) void*)l, 16, 0, 0);
}

// ---------------- x fp32 -> bf16 ----------------
__global__ __launch_bounds__(256) void k_cvt_x(const float* __restrict__ x,
                                               bf16* __restrict__ xb) {
  const int64_t i = (int64_t)blockIdx.x * 256 + threadIdx.x;
  const float4* src = (const float4*)x;
  float4 a = src[i * 2];
  float4 b = src[i * 2 + 1];
  bf16x8 o;
  o[0] = (bf16)a.x; o[1] = (bf16)a.y; o[2] = (bf16)a.z; o[3] = (bf16)a.w;
  o[4] = (bf16)b.x; o[5] = (bf16)b.y; o[6] = (bf16)b.z; o[7] = (bf16)b.w;
  *(bf16x8*)(xb + i * 8) = o;
}

// ---------------- weights -> bf16 transposed (B^T layout rows) ----------------
// wt[n][k]: n in [0,768) Wq, [768,1536) Wk, [1536,2304) Wv, [2304,3072) Wo
__global__ __launch_bounds__(256) void k_wt(const float* __restrict__ Wq,
                                            const float* __restrict__ Wk,
                                            const float* __restrict__ Wv,
                                            const float* __restrict__ Wo,
                                            bf16* __restrict__ wt) {
  __shared__ float tile[32][33];
  const int n0 = blockIdx.x * 32;   // 0..3071
  const int k0 = blockIdx.y * 32;   // 0..767
  const float* W;
  int nc;
  if (n0 < 768)        { W = Wq; nc = n0; }
  else if (n0 < 1536)  { W = Wk; nc = n0 - 768; }
  else if (n0 < 2304)  { W = Wv; nc = n0 - 1536; }
  else                 { W = Wo; nc = n0 - 2304; }
  const int tx = threadIdx.x & 31, ty = threadIdx.x >> 5;
  for (int r = ty; r < 32; r += 8)
    tile[r][tx] = W[(int64_t)(k0 + r) * 768 + nc + tx];
  __syncthreads();
  for (int r = ty; r < 32; r += 8)
    wt[(int64_t)(n0 + r) * 768 + k0 + tx] = (bf16)tile[tx][r];
}

// ---------------- QKV GEMM + bias + RoPE + scatter ----------------
// Main loop: 256x256 tile, BK=64, 8 waves (2Mx4N), 128 KiB LDS double-buffer,
// stage(t+1)-before-compute(t), chunk-XOR swizzle. LDS-staged coalesced epilogue.
__global__ __launch_bounds__(512, 2) void k_qkv(const bf16* __restrict__ xb,
                                                const bf16* __restrict__ wt,
                                                const float* __restrict__ bq,
                                                const float* __restrict__ bk,
                                                const float* __restrict__ bv,
                                                bf16* __restrict__ qb,
                                                bf16* __restrict__ kb,
                                                bf16* __restrict__ vt) {
  extern __shared__ char smem_raw[];
  bf16* smem = (bf16*)smem_raw;          // [2][A:16384 | B:16384] elements
  const int tid = threadIdx.x;
  const int w = tid >> 6, lane = tid & 63, quad = lane >> 4, l16 = lane & 15;
  const int wr = w >> 2, wc = w & 3;     // 2 x 4 wave grid
  const int kap = l16 & 7;               // per-thread chunk XOR key
  // ---- L2-supertiled decode: 1152 blocks = 8 xcd * 16 m * 9 n (n innermost) ----
  const int bid = blockIdx.x;
  const int xcd = bid & 7;
  const int loc = bid >> 3;              // 0..143
  const int m0  = (xcd * 16 + loc / 9) * 256;
  const int n0  = (loc % 9) * 256;
  // staging: per gld_lds a wave writes 8 LDS rows; lane supplies row lane>>3,
  // chunk lane&7, fetched from global chunk (lane&7)^((lane>>3)&7)  (involution)
  const int srow = w * 8 + (lane >> 3);
  const int cgo  = ((lane & 7) ^ ((lane >> 3) & 7)) * 8;
  const bf16* Ag = xb + (int64_t)(m0 + srow) * 768 + cgo;
  const bf16* Bg = wt + (int64_t)(n0 + srow) * 768 + cgo;

  auto stage = [&](int kt, int p) {
    bf16* LA = smem + p * 32768 + w * 512;
    bf16* LB = LA + 16384;
    const bf16* GA = Ag + kt * 64;
    const bf16* GB = Bg + kt * 64;
#pragma unroll
    for (int rd = 0; rd < 4; ++rd) {
      gld_lds16(GA + rd * 49152, LA + rd * 4096);   // 64 rows per round
      gld_lds16(GB + rd * 49152, LB + rd * 4096);
    }
  };

  f32x4 acc[8][4] = {};
  stage(0, 0);
  __syncthreads();
  for (int t = 0; t < 12; ++t) {
    if (t < 11) stage(t + 1, (t + 1) & 1);      // overlaps this tile's compute
    __builtin_amdgcn_sched_barrier(0);          // keep stage issue early
    const bf16* A = smem + (t & 1) * 32768;
    const bf16* B = A + 16384;
    bf16x8 bfr[4][2];
#pragma unroll
    for (int ni = 0; ni < 4; ++ni)
#pragma unroll
      for (int kk = 0; kk < 2; ++kk)
        bfr[ni][kk] = *(const bf16x8*)&B[(wc * 64 + ni * 16 + l16) * 64 +
                                         (((kk * 4 + quad) ^ kap) * 8)];
#pragma unroll
    for (int mh = 0; mh < 2; ++mh) {
      bf16x8 afr[4][2];
#pragma unroll
      for (int mi = 0; mi < 4; ++mi)
#pragma unroll
        for (int kk = 0; kk < 2; ++kk)
          afr[mi][kk] = *(const bf16x8*)&A[(wr * 128 + mh * 64 + mi * 16 + l16) * 64 +
                                           (((kk * 4 + quad) ^ kap) * 8)];
      __builtin_amdgcn_s_setprio(1);
#pragma unroll
      for (int mi = 0; mi < 4; ++mi)
#pragma unroll
        for (int ni = 0; ni < 4; ++ni)
#pragma unroll
          for (int kk = 0; kk < 2; ++kk)
            acc[mh * 4 + mi][ni] = MFMA_BF16(afr[mi][kk], bfr[ni][kk], acc[mh * 4 + mi][ni]);
      __builtin_amdgcn_s_setprio(0);
    }
    __syncthreads();   // drains vmcnt: stage(t+1) had the whole compute to land
  }
  // ---- epilogue: LDS-staged coalesced writes ----
  const int sec = n0 / 768;            // block-uniform: 0=q 1=k 2=v
  const int h0 = (n0 % 768) >> 6;      // first head of this block's n-range
  const float* bias_p = (sec == 0) ? bq : (sec == 1) ? bk : bv;
  char* eb = (char*)smem;
  const int64_t obase = (int64_t)(m0 >> 8) * 12 * 16384;  // bt * 12 heads * 64*256
  if (sec == 2) {
    // stage v as [hh][hd][p] (rows 512B), 16B-chunk swizzle: chunk' = (p>>3)^(hd&15)
#pragma unroll
    for (int ni = 0; ni < 4; ++ni) {
      const int nn = wc * 64 + ni * 16 + l16;   // 0..255
      const int hh = nn >> 6, hd = nn & 63;
      const float bias = bias_p[(n0 % 768) + nn];
#pragma unroll
      for (int mi = 0; mi < 8; ++mi) {
        const int p = wr * 128 + mi * 16 + quad * 4;   // local row 0..255 (r in-vec)
        bf16x4 pk;
#pragma unroll
        for (int r = 0; r < 4; ++r) pk[r] = (bf16)(acc[mi][ni][r] + bias);
        *(bf16x4*)(eb + hh * 32768 + hd * 512 +
                   ((((p >> 3) ^ (hd & 15)) << 4) | (((p >> 2) & 1) << 3))) = pk;
      }
    }
    __syncthreads();
#pragma unroll
    for (int it = 0; it < 16; ++it) {
      const int lin = (it * 512 + tid) * 16;   // byte offset in LDS
      const int hh = lin >> 15;
      const int rem = lin & 32767;
      const int hd = rem >> 9;
      const int cs = (rem >> 4) & 31;
      const int pc = cs ^ (hd & 15);           // un-swizzle: global p-chunk
      bf16x8 val = *(const bf16x8*)(eb + lin);
      *(bf16x8*)&vt[obase + ((int64_t)(h0 + hh) * 64 + hd) * 256 + pc * 8] = val;
    }
  } else {
    bf16* dst = (sec == 0) ? qb : kb;
    const float L2C = 0.83048202372184058696f;  // log2(10000)/16
    // stage q/k as [hh][p][hd] (rows 128B), 16B-chunk swizzle: chunk' = (hd>>3)^(p&7)
#pragma unroll
    for (int ni = 0; ni < 4; ++ni) {
      const int nn = wc * 64 + ni * 16 + l16;
      const int hh = nn >> 6, hd = nn & 63;
      const float bias = bias_p[(n0 % 768) + nn];
      const int j = (hd & 31) >> 1;
      const float invf = exp2f(-(float)j * L2C);
      const bool odd = (hd & 1);
      const bool isx = (hd < 32);
      // pos = isx ? (p&15) = quad*4+r  :  (p>>4) = wr*8+mi  — hoist sincos
      float snt[8], cst[8];
      if (isx) {
#pragma unroll
        for (int r = 0; r < 4; ++r)
          __sincosf((float)(quad * 4 + r) * invf, &snt[r], &cst[r]);
      } else {
#pragma unroll
        for (int mi = 0; mi < 8; ++mi)
          __sincosf((float)(wr * 8 + mi) * invf, &snt[mi], &cst[mi]);
      }
#pragma unroll
      for (int mi = 0; mi < 8; ++mi) {
#pragma unroll
        for (int r = 0; r < 4; ++r) {
          const int p = wr * 128 + mi * 16 + quad * 4 + r;  // local row 0..255
          float v = acc[mi][ni][r] + bias;
          float pv = __shfl_xor(v, 1, 64);  // partner column (hd ^ 1), same row
          const float sn = isx ? snt[r] : snt[mi];
          const float cz = isx ? cst[r] : cst[mi];
          float o = odd ? (v * cz + pv * sn) : (v * cz - pv * sn);
          *(bf16*)(eb + hh * 32768 + p * 128 +
                   ((((hd >> 3) ^ (p & 7)) << 4) | ((hd & 7) << 1))) = (bf16)o;
        }
      }
    }
    __syncthreads();
#pragma unroll
    for (int it = 0; it < 16; ++it) {
      const int lin = (it * 512 + tid) * 16;
      const int hh = lin >> 15;
      const int rem = lin & 32767;
      const int p = rem >> 7;
      const int cs = (rem >> 4) & 7;
      const int hc = cs ^ (p & 7);             // un-swizzle: global hd-chunk
      bf16x8 val = *(const bf16x8*)(eb + lin);
      *(bf16x8*)&dst[obase + ((int64_t)(h0 + hh) * 256 + p) * 64 + hc * 8] = val;
    }
  }
}

// ---------------- attention: per (b,t,h) block ----------------
// NEW: K and V staged ONCE per block into LDS (16B-chunk XOR swizzle via
// pre-swizzled global source, gld_lds dest linear). 8 waves x 32 q-rows.
// MFMA chains feed from LDS (12cy) instead of global (200-900cy); intra-block
// K/V reuse 16x. Per-wave plds round-trip keeps verified in-wave fences.
__global__ __launch_bounds__(512, 2) void k_attn(bf16* qy,
                                                 const bf16* __restrict__ kb,
                                                 const bf16* __restrict__ vt) {
  extern __shared__ char smem_raw[];
  bf16* lK = (bf16*)smem_raw;           // [256][64] swizzled, 32 KB
  bf16* lV = lK + 16384;                // [64][256] swizzled, 32 KB
  bf16* plds = lV + 16384;              // 8 waves x 16 x 264, 66 KB
  const int tid = threadIdx.x;
  const int w = tid >> 6, lane = tid & 63, quad = lane >> 4, l16 = lane & 15;
  const int64_t base = (int64_t)blockIdx.x * 16384;  // 256*64
  bf16* Q = qy + base;
  const bf16* K = kb + base;
  const bf16* V = vt + base;
  bf16* pl = plds + w * 4224;
  // ---- stage K,V -> LDS (once). chunk' = chunk ^ (row&7), 16B chunks ----
#pragma unroll
  for (int rd = 0; rd < 4; ++rd) {
    const int ci = rd * 512 + tid;
    const int krow = ci >> 3, kch = ci & 7;          // K: 8 chunks/row (128B)
    gld_lds16(K + krow * 64 + ((kch ^ (krow & 7)) << 3),
              lK + (rd * 512 + w * 64) * 8);
    const int vrow = ci >> 5, vch = ci & 31;         // V: 32 chunks/row (512B)
    gld_lds16(V + vrow * 256 + ((vch ^ (vrow & 7)) << 3),
              lV + (rd * 512 + w * 64) * 8);
  }
  __syncthreads();   // K/V visible; read-only below — no further block barriers
  for (int s = 0; s < 2; ++s) {
    const int r0 = w * 32 + s * 16;
    bf16x8 qf0 = *(const bf16x8*)&Q[(r0 + l16) * 64 + quad * 8];
    bf16x8 qf1 = *(const bf16x8*)&Q[(r0 + l16) * 64 + 32 + quad * 8];
    f32x4 sacc[16] = {};
    __builtin_amdgcn_s_setprio(1);
#pragma unroll
    for (int ct = 0; ct < 16; ++ct) {
      const int kr = ct * 16 + l16;
      bf16x8 kf0 = *(const bf16x8*)&lK[kr * 64 + ((quad ^ (kr & 7)) << 3)];
      bf16x8 kf1 = *(const bf16x8*)&lK[kr * 64 + (((quad + 4) ^ (kr & 7)) << 3)];
      sacc[ct] = MFMA_BF16(qf0, kf0, sacc[ct]);
      sacc[ct] = MFMA_BF16(qf1, kf1, sacc[ct]);
    }
    __builtin_amdgcn_s_setprio(0);
    // softmax over 256 cols; rows live as (quad,reg); cols spread over 16 lanes x 16 tiles
    float mx[4] = {-3e38f, -3e38f, -3e38f, -3e38f};
#pragma unroll
    for (int ct = 0; ct < 16; ++ct)
#pragma unroll
      for (int r = 0; r < 4; ++r) mx[r] = fmaxf(mx[r], sacc[ct][r]);
#pragma unroll
    for (int d = 1; d < 16; d <<= 1)
#pragma unroll
      for (int r = 0; r < 4; ++r) mx[r] = fmaxf(mx[r], __shfl_xor(mx[r], d, 64));
    float sm[4] = {0.f, 0.f, 0.f, 0.f};
#pragma unroll
    for (int ct = 0; ct < 16; ++ct)
#pragma unroll
      for (int r = 0; r < 4; ++r) {
        float e = __expf((sacc[ct][r] - mx[r]) * 0.125f);
        sacc[ct][r] = e;
        sm[r] += e;
      }
#pragma unroll
    for (int d = 1; d < 16; d <<= 1)
#pragma unroll
      for (int r = 0; r < 4; ++r) sm[r] += __shfl_xor(sm[r], d, 64);
    // P: C-layout -> LDS -> A-layout (same-wave cross-lane round-trip)
#pragma unroll
    for (int ct = 0; ct < 16; ++ct)
#pragma unroll
      for (int r = 0; r < 4; ++r)
        pl[(quad * 4 + r) * 264 + ct * 16 + l16] = (bf16)sacc[ct][r];
    asm volatile("s_waitcnt lgkmcnt(0)" ::: "memory");  // in-wave: writes landed
    __builtin_amdgcn_sched_barrier(0);
    f32x4 oacc[4] = {};
    __builtin_amdgcn_s_setprio(1);
#pragma unroll
    for (int kc = 0; kc < 8; ++kc) {
      bf16x8 pf = *(const bf16x8*)&pl[l16 * 264 + kc * 32 + quad * 8];
#pragma unroll
      for (int nt = 0; nt < 4; ++nt) {
        const int vr = nt * 16 + l16;
        bf16x8 vf = *(const bf16x8*)&lV[vr * 256 + (((kc * 4 + quad) ^ (vr & 7)) << 3)];
        oacc[nt] = MFMA_BF16(pf, vf, oacc[nt]);
      }
    }
    __builtin_amdgcn_s_setprio(0);
    float inv[4];
#pragma unroll
    for (int r = 0; r < 4; ++r) inv[r] = 1.0f / sm[r];
#pragma unroll
    for (int nt = 0; nt < 4; ++nt)
#pragma unroll
      for (int r = 0; r < 4; ++r)
        Q[(r0 + quad * 4 + r) * 64 + nt * 16 + l16] = (bf16)(oacc[nt][r] * inv[r]);
    asm volatile("" ::: "memory");  // keep next-s pl writes below this-s pl reads
  }
}

// ---------------- out GEMM: y(b,t,h,p,hd) @ Wo -> d_out fp32 ----------------
// 2-phase 256-tile template: BM=256, BN=128, BK=64, 8 waves (4M x 2N), 96 KiB
// LDS double-buffer, stage-before-compute, chunk-XOR swizzle. A K-tile = one
// head: A is a fully contiguous 32 KiB block. 768 blocks = 8 xcd * 16 m * 6 n.
__global__ __launch_bounds__(512, 2) void k_out(const bf16* __restrict__ yb,
                                                const bf16* __restrict__ wt,
                                                float* __restrict__ out) {
  extern __shared__ char smem_raw[];
  bf16* smem = (bf16*)smem_raw;          // 2 bufs x (A:16384 | B:8192) elems = 96 KiB
  const int tid = threadIdx.x;
  const int w = tid >> 6, lane = tid & 63, quad = lane >> 4, l16 = lane & 15;
  const int wr = w >> 1, wc = w & 1;     // 4M x 2N wave grid
  const int bid = blockIdx.x;
  const int xcd = bid & 7;
  const int loc = bid >> 3;              // 0..95
  const int m0  = (xcd * 16 + loc / 6) * 256;
  const int n0  = (loc % 6) * 128;
  const int bt  = m0 >> 8;               // one (b,t) per block
  // staging: rows of 64 elems (128B); per gld_lds a wave covers 8 rows x 8 chunks
  const int srow = w * 8 + (lane >> 3);
  const int cgo  = (((lane & 7) ^ ((lane >> 3) & 7)) * 8);
  const bf16* Bg0 = wt + (int64_t)(2304 + n0 + srow) * 768 + cgo;

  auto stage = [&](int kt, int p) {
    bf16* LA = smem + p * 24576 + w * 512;
    bf16* LB = smem + p * 24576 + 16384 + w * 512;
    const bf16* GA = yb + (int64_t)(bt * 12 + kt) * 16384 + srow * 64 + cgo;
    const bf16* GB = Bg0 + kt * 64;
#pragma unroll
    for (int rd = 0; rd < 4; ++rd)
      gld_lds16(GA + rd * 4096, LA + rd * 4096);    // 64 rows per round
#pragma unroll
    for (int rd = 0; rd < 2; ++rd)
      gld_lds16(GB + rd * 49152, LB + rd * 4096);
  };

  f32x4 acc[4][4] = {};
  stage(0, 0);
  __syncthreads();
  const int rkey8 = (l16 & 7) * 8;
  for (int t = 0; t < 12; ++t) {
    if (t < 11) stage(t + 1, (t + 1) & 1);   // overlaps this tile's compute
    __builtin_amdgcn_sched_barrier(0);
    const bf16* A = smem + (t & 1) * 24576;
    const bf16* B = A + 16384;
    bf16x8 bfr[4][2];
#pragma unroll
    for (int ni = 0; ni < 4; ++ni)
#pragma unroll
      for (int kk = 0; kk < 2; ++kk)
        bfr[ni][kk] = *(const bf16x8*)&B[(wc * 64 + ni * 16 + l16) * 64 +
                                         (((kk * 4 + quad) * 8) ^ rkey8)];
    bf16x8 afr[4][2];
#pragma unroll
    for (int mi = 0; mi < 4; ++mi)
#pragma unroll
      for (int kk = 0; kk < 2; ++kk)
        afr[mi][kk] = *(const bf16x8*)&A[(wr * 64 + mi * 16 + l16) * 64 +
                                         (((kk * 4 + quad) * 8) ^ rkey8)];
    __builtin_amdgcn_s_setprio(1);
#pragma unroll
    for (int mi = 0; mi < 4; ++mi)
#pragma unroll
      for (int ni = 0; ni < 4; ++ni)
#pragma unroll
        for (int kk = 0; kk < 2; ++kk)
          acc[mi][ni] = MFMA_BF16(afr[mi][kk], bfr[ni][kk], acc[mi][ni]);
    __builtin_amdgcn_s_setprio(0);
    __syncthreads();
  }
#pragma unroll
  for (int mi = 0; mi < 4; ++mi)
#pragma unroll
    for (int ni = 0; ni < 4; ++ni) {
      const int rg = m0 + wr * 64 + mi * 16 + quad * 4;
      const int cg = n0 + wc * 64 + ni * 16 + l16;
#pragma unroll
      for (int r = 0; r < 4; ++r)
        out[(int64_t)(rg + r) * 768 + cg] = acc[mi][ni][r];
    }
}

extern "C" void kernel_launch(void* const* d_in, const int* in_sizes, int n_in,
                              void* d_out, int out_size, void* d_ws, size_t ws_size,
                              hipStream_t stream) {
  const float* x  = (const float*)d_in[0];
  const float* Wq = (const float*)d_in[1];
  const float* bq = (const float*)d_in[2];
  const float* Wk = (const float*)d_in[3];
  const float* bk = (const float*)d_in[4];
  const float* Wv = (const float*)d_in[5];
  const float* bv = (const float*)d_in[6];
  const float* Wo = (const float*)d_in[7];
  float* out = (float*)d_out;

  uint8_t* ws = (uint8_t*)d_ws;
  const size_t SZ = (size_t)25165824 * 2;        // one (B,T,H,P,HD) bf16 tensor
  bf16* qy = (bf16*)ws;                          // q, later reused as y
  bf16* kb = (bf16*)(ws + SZ);
  bf16* vt = (bf16*)(ws + 2 * SZ);
  bf16* wt = (bf16*)(ws + 3 * SZ);               // 3072x768 bf16
  bf16* xb = (bf16*)d_out;                       // x-bf16 scratch inside output buffer

  static int attr_set = 0;
  if (!attr_set) {
    (void)hipFuncSetAttribute((const void*)k_qkv,
                              hipFuncAttributeMaxDynamicSharedMemorySize, 131072);
    (void)hipFuncSetAttribute((const void*)k_attn,
                              hipFuncAttributeMaxDynamicSharedMemorySize, 133120);
    (void)hipFuncSetAttribute((const void*)k_out,
                              hipFuncAttributeMaxDynamicSharedMemorySize, 98304);
    attr_set = 1;
  }

  k_cvt_x<<<12288, 256, 0, stream>>>(x, xb);
  k_wt<<<dim3(96, 24), 256, 0, stream>>>(Wq, Wk, Wv, Wo, wt);
  k_qkv<<<1152, 512, 131072, stream>>>(xb, wt, bq, bk, bv, qy, kb, vt);
  k_attn<<<1536, 512, 133120, stream>>>(qy, kb, vt);
  k_out<<<768, 512, 98304, stream>>>(qy, wt, out);
}